// Round 9
// baseline (190.591 us; speedup 1.0000x reference)
//
#include <hip/hip_runtime.h>

// 2-layer GAT forward, N nodes, K=16 neighbors (row-sorted, exactly 16/dst),
// feats 128 -> 64 -> 64, fp32 in/out.
//
// K1: h1 = x @ W1 (fp16 MFMA) + scores s1a,s2a
// K2: attn(h1) -> xm fp16     [8 nodes/wave, rows gathered BEFORE softmax]
// K3: h2 = xm @ W2 + scores   [B operand entirely in registers]
// K4: attn(h2) -> out fp32
//
// Measured structure notes:
//  - R6: fusing attn+gemm cost occupancy (13%) -> net zero. Keep de-fused.
//  - R7: __launch_bounds__(256,4) strangled VGPRs -> serialized prefetch,
//    2.8x gemm1 regression. Keep (256,2) + 48-rows-upfront loads.
//  - R8: W-lo correction dropped; absmax 1.95e-3 vs 5.66e-3 threshold.
//  - R9: attn reordered so the 16 row-gathers issue before the s2/softmax
//    chain (they only depend on col-bpermute), 8 nodes/wave (1 KB/gather).

typedef __attribute__((ext_vector_type(8))) _Float16 f16x8;
typedef __attribute__((ext_vector_type(4))) float floatx4;

static __device__ inline float ubitf(unsigned u) { union { unsigned u; float f; } v; v.u = u; return v.f; }
static __device__ inline unsigned fbitu(float f) { union { float f; unsigned u; } v; v.f = f; return v.u; }

// ---------------- K1: h1 = X(fp32)[n,128] @ W1 -> fp16 + scores -------------
template<int KD>
__global__ __launch_bounds__(256, 2) void gemm_score_f16(
    const float* __restrict__ X, const float* __restrict__ W,
    const float* __restrict__ av, _Float16* __restrict__ H,
    float* __restrict__ s1, float* __restrict__ s2, int n)
{
    constexpr int NKT = KD / 32;
    constexpr int NF = NKT * 4 * 64;
    __shared__ f16x8 Bs[NF];
    const int tid = threadIdx.x;

    for (int f = tid; f < NF; f += 256) {
        const int ln = f & 63, ntk = f >> 6;
        const int kt = ntk >> 2, nt = ntk & 3;
        const int kbase = kt * 32 + (ln >> 4) * 8;
        const int ccol = nt * 16 + (ln & 15);
        f16x8 hh;
#pragma unroll
        for (int j = 0; j < 8; j++)
            hh[j] = (_Float16)W[(kbase + j) * 64 + ccol];
        Bs[f] = hh;
    }
    __syncthreads();

    const int wave = tid >> 6, lane = tid & 63;
    const int quad = lane >> 4, l15 = lane & 15;
    const int r0 = blockIdx.x * 192 + wave * 48;

    float a1c[4], a2c[4];
#pragma unroll
    for (int nt = 0; nt < 4; nt++) {
        a1c[nt] = av[nt * 16 + l15];
        a2c[nt] = av[64 + nt * 16 + l15];
    }

    float4 raw[NKT][3][2];
#pragma unroll
    for (int rb = 0; rb < 3; rb++) {
        int ra = r0 + rb * 16 + l15; if (ra > n - 1) ra = n - 1;
        const float* xp = &X[(size_t)ra * KD + quad * 8];
#pragma unroll
        for (int kt = 0; kt < NKT; kt++) {
            raw[kt][rb][0] = *(const float4*)(xp + kt * 32);
            raw[kt][rb][1] = *(const float4*)(xp + kt * 32 + 4);
        }
    }
    f16x8 A[NKT][3];
#pragma unroll
    for (int kt = 0; kt < NKT; kt++)
#pragma unroll
        for (int rb = 0; rb < 3; rb++) {
            f16x8 a;
            a[0] = (_Float16)raw[kt][rb][0].x; a[1] = (_Float16)raw[kt][rb][0].y;
            a[2] = (_Float16)raw[kt][rb][0].z; a[3] = (_Float16)raw[kt][rb][0].w;
            a[4] = (_Float16)raw[kt][rb][1].x; a[5] = (_Float16)raw[kt][rb][1].y;
            a[6] = (_Float16)raw[kt][rb][1].z; a[7] = (_Float16)raw[kt][rb][1].w;
            A[kt][rb] = a;
        }

    floatx4 acc[4][3];
#pragma unroll
    for (int nt = 0; nt < 4; nt++)
#pragma unroll
        for (int rb = 0; rb < 3; rb++) acc[nt][rb] = (floatx4){0, 0, 0, 0};

#pragma unroll
    for (int kt = 0; kt < NKT; kt++)
#pragma unroll
        for (int nt = 0; nt < 4; nt++) {
            const f16x8 b = Bs[(kt * 4 + nt) * 64 + lane];
#pragma unroll
            for (int rb = 0; rb < 3; rb++)
                acc[nt][rb] = __builtin_amdgcn_mfma_f32_16x16x32_f16(A[kt][rb], b, acc[nt][rb], 0, 0, 0);
        }

#pragma unroll
    for (int rb = 0; rb < 3; rb++) {
        float p1[4] = {0, 0, 0, 0}, p2[4] = {0, 0, 0, 0};
#pragma unroll
        for (int nt = 0; nt < 4; nt++)
#pragma unroll
            for (int reg = 0; reg < 4; reg++) {
                const int r = r0 + rb * 16 + quad * 4 + reg;
                if (r < n) H[(size_t)r * 64 + nt * 16 + l15] = (_Float16)acc[nt][rb][reg];
                p1[reg] = fmaf(acc[nt][rb][reg], a1c[nt], p1[reg]);
                p2[reg] = fmaf(acc[nt][rb][reg], a2c[nt], p2[reg]);
            }
#pragma unroll
        for (int m = 1; m < 16; m <<= 1)
#pragma unroll
            for (int reg = 0; reg < 4; reg++) {
                p1[reg] += __shfl_xor(p1[reg], m, 64);
                p2[reg] += __shfl_xor(p2[reg], m, 64);
            }
        if (l15 == 0)
#pragma unroll
            for (int reg = 0; reg < 4; reg++) {
                const int r = r0 + rb * 16 + quad * 4 + reg;
                if (r < n) { s1[r] = p1[reg]; s2[r] = p2[reg]; }
            }
    }
}

// ---------------- K3: h2 = Xm(fp16)[n,64] @ W2 -> fp16 + scores -------------
__global__ __launch_bounds__(256, 2) void gemm2_score(
    const _Float16* __restrict__ Xm, const float* __restrict__ W,
    const float* __restrict__ av, _Float16* __restrict__ H,
    float* __restrict__ s1, float* __restrict__ s2, int n)
{
    constexpr int NKT = 2;
    constexpr int NF = NKT * 4 * 64;
    __shared__ f16x8 Bs[NF];
    const int tid = threadIdx.x;

    for (int f = tid; f < NF; f += 256) {
        const int ln = f & 63, ntk = f >> 6;
        const int kt = ntk >> 2, nt = ntk & 3;
        const int kbase = kt * 32 + (ln >> 4) * 8;
        const int ccol = nt * 16 + (ln & 15);
        f16x8 hh;
#pragma unroll
        for (int j = 0; j < 8; j++)
            hh[j] = (_Float16)W[(kbase + j) * 64 + ccol];
        Bs[f] = hh;
    }
    __syncthreads();

    const int wave = tid >> 6, lane = tid & 63;
    const int quad = lane >> 4, l15 = lane & 15;
    const int r0 = blockIdx.x * 192 + wave * 48;

    f16x8 br[NKT][4];
#pragma unroll
    for (int kt = 0; kt < NKT; kt++)
#pragma unroll
        for (int nt = 0; nt < 4; nt++)
            br[kt][nt] = Bs[(kt * 4 + nt) * 64 + lane];

    float a1c[4], a2c[4];
#pragma unroll
    for (int nt = 0; nt < 4; nt++) {
        a1c[nt] = av[nt * 16 + l15];
        a2c[nt] = av[64 + nt * 16 + l15];
    }

    f16x8 A[NKT][3];
#pragma unroll
    for (int rb = 0; rb < 3; rb++) {
        int ra = r0 + rb * 16 + l15; if (ra > n - 1) ra = n - 1;
        const _Float16* xp = &Xm[(size_t)ra * 64 + quad * 8];
#pragma unroll
        for (int kt = 0; kt < NKT; kt++)
            A[kt][rb] = *(const f16x8*)(xp + kt * 32);
    }

    floatx4 acc[4][3];
#pragma unroll
    for (int nt = 0; nt < 4; nt++)
#pragma unroll
        for (int rb = 0; rb < 3; rb++) acc[nt][rb] = (floatx4){0, 0, 0, 0};

#pragma unroll
    for (int kt = 0; kt < NKT; kt++)
#pragma unroll
        for (int nt = 0; nt < 4; nt++)
#pragma unroll
            for (int rb = 0; rb < 3; rb++)
                acc[nt][rb] = __builtin_amdgcn_mfma_f32_16x16x32_f16(A[kt][rb], br[kt][nt], acc[nt][rb], 0, 0, 0);

#pragma unroll
    for (int rb = 0; rb < 3; rb++) {
        float p1[4] = {0, 0, 0, 0}, p2[4] = {0, 0, 0, 0};
#pragma unroll
        for (int nt = 0; nt < 4; nt++)
#pragma unroll
            for (int reg = 0; reg < 4; reg++) {
                const int r = r0 + rb * 16 + quad * 4 + reg;
                if (r < n) H[(size_t)r * 64 + nt * 16 + l15] = (_Float16)acc[nt][rb][reg];
                p1[reg] = fmaf(acc[nt][rb][reg], a1c[nt], p1[reg]);
                p2[reg] = fmaf(acc[nt][rb][reg], a2c[nt], p2[reg]);
            }
#pragma unroll
        for (int m = 1; m < 16; m <<= 1)
#pragma unroll
            for (int reg = 0; reg < 4; reg++) {
                p1[reg] += __shfl_xor(p1[reg], m, 64);
                p2[reg] += __shfl_xor(p2[reg], m, 64);
            }
        if (l15 == 0)
#pragma unroll
            for (int reg = 0; reg < 4; reg++) {
                const int r = r0 + rb * 16 + quad * 4 + reg;
                if (r < n) { s1[r] = p1[reg]; s2[r] = p2[reg]; }
            }
    }
}

// ---------------- K2/K4: attention, 8 nodes/wave, 8 lanes/node --------------
// lane = g*8+j (node g in [0,8), j in [0,8)); lane owns feats j*8..j*8+7.
// Order matters: srck only depends on col, so ALL 16 row gathers (1 KB each)
// are issued before the s2-gather/softmax chain, which then runs while the
// rows are in flight.
template<typename OT>
__global__ __launch_bounds__(512) void attn(
    const _Float16* __restrict__ H, const float* __restrict__ s1,
    const float* __restrict__ s2, const int* __restrict__ col,
    const float* __restrict__ bias, OT* __restrict__ out, int n)
{
    const int lane = threadIdx.x & 63;
    const int wv = threadIdx.x >> 6;                 // 0..7
    const int g = lane >> 3, j = lane & 7;
    const int dst = blockIdx.x * 64 + wv * 8 + g;
    const int dc = (dst > n - 1) ? (n - 1) : dst;

    const int c0 = col[dc * 16 + j];
    const int c1 = col[dc * 16 + 8 + j];

    // row indices via bpermute (LDS-speed, independent of scores)
    const int bb4 = (lane & 56) << 2;                // node-group base byte idx
    int srck[16];
#pragma unroll
    for (int k = 0; k < 8; k++) {
        srck[k]     = __builtin_amdgcn_ds_bpermute(bb4 + 4 * k, c0);
        srck[k + 8] = __builtin_amdgcn_ds_bpermute(bb4 + 4 * k, c1);
    }
    // issue all 16 row gathers NOW (16 KB/wave in flight)
    f16x8 hv[16];
#pragma unroll
    for (int k = 0; k < 16; k++)
        hv[k] = *(const f16x8*)&H[(size_t)srck[k] * 64 + j * 8];

    // score chain overlaps the row gathers
    const float s1d = s1[dc];
    float e0 = s1d + s2[c0];
    float e1 = s1d + s2[c1];
    e0 = (e0 > 0.0f) ? e0 : 0.2f * e0;               // leaky_relu 0.2
    e1 = (e1 > 0.0f) ? e1 : 0.2f * e1;
    float m = fmaxf(e0, e1);
    m = fmaxf(m, __shfl_xor(m, 1, 64));
    m = fmaxf(m, __shfl_xor(m, 2, 64));
    m = fmaxf(m, __shfl_xor(m, 4, 64));
    const float p0 = __expf(e0 - m), p1 = __expf(e1 - m);
    float s = p0 + p1;
    s += __shfl_xor(s, 1, 64); s += __shfl_xor(s, 2, 64); s += __shfl_xor(s, 4, 64);
    const float inv = 1.0f / s;
    const float att0 = p0 * inv, att1 = p1 * inv;

    float attk[16];
#pragma unroll
    for (int k = 0; k < 8; k++) {
        attk[k]     = ubitf((unsigned)__builtin_amdgcn_ds_bpermute(bb4 + 4 * k, (int)fbitu(att0)));
        attk[k + 8] = ubitf((unsigned)__builtin_amdgcn_ds_bpermute(bb4 + 4 * k, (int)fbitu(att1)));
    }

    float acc[8] = {0, 0, 0, 0, 0, 0, 0, 0};
#pragma unroll
    for (int k = 0; k < 16; k++)
#pragma unroll
        for (int q = 0; q < 8; q++)
            acc[q] = fmaf(attk[k], (float)hv[k][q], acc[q]);

    if (dst < n) {
        float4 b0 = *(const float4*)&bias[j * 8];
        float4 b1 = *(const float4*)&bias[j * 8 + 4];
        const float o0 = fmaxf(acc[0] + b0.x, 0.0f);
        const float o1 = fmaxf(acc[1] + b0.y, 0.0f);
        const float o2 = fmaxf(acc[2] + b0.z, 0.0f);
        const float o3 = fmaxf(acc[3] + b0.w, 0.0f);
        const float o4 = fmaxf(acc[4] + b1.x, 0.0f);
        const float o5 = fmaxf(acc[5] + b1.y, 0.0f);
        const float o6 = fmaxf(acc[6] + b1.z, 0.0f);
        const float o7 = fmaxf(acc[7] + b1.w, 0.0f);
        if constexpr (sizeof(OT) == 2) {
            f16x8 o;
            o[0] = (_Float16)o0; o[1] = (_Float16)o1; o[2] = (_Float16)o2; o[3] = (_Float16)o3;
            o[4] = (_Float16)o4; o[5] = (_Float16)o5; o[6] = (_Float16)o6; o[7] = (_Float16)o7;
            *(f16x8*)&out[(size_t)dst * 64 + j * 8] = o;
        } else {
            float4 w0, w1;
            w0.x = o0; w0.y = o1; w0.z = o2; w0.w = o3;
            w1.x = o4; w1.y = o5; w1.z = o6; w1.w = o7;
            *(float4*)&out[(size_t)dst * 64 + j * 8] = w0;
            *(float4*)&out[(size_t)dst * 64 + j * 8 + 4] = w1;
        }
    }
}

extern "C" void kernel_launch(void* const* d_in, const int* in_sizes, int n_in,
                              void* d_out, int out_size, void* d_ws, size_t ws_size,
                              hipStream_t stream)
{
    const float* x        = (const float*)d_in[0];
    const int*   edge_col = (const int*)  d_in[2];
    const float* W1       = (const float*)d_in[3];
    const float* a1       = (const float*)d_in[4];
    const float* b1       = (const float*)d_in[5];
    const float* W2       = (const float*)d_in[6];
    const float* a2       = (const float*)d_in[7];
    const float* b2       = (const float*)d_in[8];
    const int n = in_sizes[0] / 128;     // 100000

    _Float16* h1 = (_Float16*)d_ws;                  // n*64 fp16
    _Float16* xm = h1 + (size_t)n * 64;              // n*64 fp16
    _Float16* h2 = xm + (size_t)n * 64;              // n*64 fp16
    float* s1a = (float*)(h2 + (size_t)n * 64);      // n
    float* s2a = s1a + n;
    float* s1b = s2a + n;
    float* s2b = s1b + n;

    const int gemm_blocks = (n + 191) / 192;         // 521
    const int agg_blocks  = (n + 63) / 64;           // 1563

    gemm_score_f16<128><<<gemm_blocks, 256, 0, stream>>>(x, W1, a1, h1, s1a, s2a, n);
    attn<_Float16><<<agg_blocks, 512, 0, stream>>>(h1, s1a, s2a, edge_col, b1, xm, n);
    gemm2_score<<<gemm_blocks, 256, 0, stream>>>(xm, W2, a2, h2, s1b, s2b, n);
    attn<float><<<agg_blocks, 512, 0, stream>>>(h2, s1b, s2b, edge_col, b2, (float*)d_out, n);
}